// Round 18
// baseline (3820.721 us; speedup 1.0000x reference)
//
#include <hip/hip_runtime.h>
#include <hip/hip_bf16.h>
#include <math.h>

// Problem constants (from reference)
#define BB 64
#define TT 2048
#define VV 4096
#define EE 128
#define H2 128
#define SS 8
#define CC 2

typedef _Float16 f16x8 __attribute__((ext_vector_type(8)));
typedef float f32x4 __attribute__((ext_vector_type(4)));

__device__ __forceinline__ float sigf(float x) { return 1.f / (1.f + __expf(-x)); }
__device__ __forceinline__ float tanh_fast(float x) { return 1.f - 2.f / (__expf(2.f * x) + 1.f); }

// LDS-only barrier: __syncthreads() emits s_waitcnt vmcnt(0) lgkmcnt(0);
// we only need LDS consistency for the h publish, so wait on lgkmcnt alone
// and let the compiler's tracked vmcnt wait land at the EG consumption point.
__device__ __forceinline__ void lds_barrier() {
    asm volatile("s_waitcnt lgkmcnt(0)" ::: "memory");
    __builtin_amdgcn_s_barrier();
    asm volatile("" ::: "memory");
}

// ---------------------------------------------------------------------------
// Kernel 1: EG gate table, float4 layout for the MFMA recurrence:
//   EG4[v][d][u] = float4{ i_u, f_u, g_u, o_u } (preact contribution + bias)
//   gate row r (0..511, PyTorch order i,f,g,o blocks of 128): u=r&127, gi=r>>7.
// ---------------------------------------------------------------------------
__global__ __launch_bounds__(256) void eg_gemm(
    const float* __restrict__ emb,
    const float* __restrict__ Wf, const float* __restrict__ bf,
    const float* __restrict__ Wb, const float* __restrict__ bb,
    float* __restrict__ EGp)
{
    __shared__ float As[64][68];
    __shared__ float Bs[64][68];

    const int tid = threadIdx.x;
    const int tx = tid & 15, ty = tid >> 4;
    const int m0 = blockIdx.y * 64;
    const int n0 = blockIdx.x * 64;

    const float* Bsrc;
    const float* bias;
    if (n0 < 512) { Bsrc = Wf + n0 * EE; bias = bf + n0; }
    else          { Bsrc = Wb + (n0 - 512) * EE; bias = bb + (n0 - 512); }

    float acc[4][4] = {};

    for (int kc = 0; kc < 2; ++kc) {
        for (int c = tid; c < 1024; c += 256) {
            int r = c >> 4, q = c & 15;
            float4 av = *(const float4*)(emb + (size_t)(m0 + r) * EE + kc * 64 + q * 4);
            As[q * 4 + 0][r] = av.x; As[q * 4 + 1][r] = av.y;
            As[q * 4 + 2][r] = av.z; As[q * 4 + 3][r] = av.w;
            float4 bv = *(const float4*)(Bsrc + (size_t)r * EE + kc * 64 + q * 4);
            Bs[q * 4 + 0][r] = bv.x; Bs[q * 4 + 1][r] = bv.y;
            Bs[q * 4 + 2][r] = bv.z; Bs[q * 4 + 3][r] = bv.w;
        }
        __syncthreads();
        #pragma unroll 8
        for (int k = 0; k < 64; ++k) {
            float4 a4 = *(const float4*)&As[k][4 * ty];
            float4 b4 = *(const float4*)&Bs[k][4 * tx];
            float a[4] = {a4.x, a4.y, a4.z, a4.w};
            float b[4] = {b4.x, b4.y, b4.z, b4.w};
            #pragma unroll
            for (int i = 0; i < 4; ++i)
                #pragma unroll
                for (int jn = 0; jn < 4; ++jn)
                    acc[i][jn] = fmaf(a[i], b[jn], acc[i][jn]);
        }
        __syncthreads();
    }

    #pragma unroll
    for (int i = 0; i < 4; ++i) {
        int m = m0 + 4 * ty + i;                 // vocab index v
        #pragma unroll
        for (int jn = 0; jn < 4; ++jn) {
            int nn = 4 * tx + jn;
            int ncol = n0 + nn;                  // combined gate col
            int d  = ncol >> 9;
            int r  = ncol & 511;
            int u  = r & 127;
            int gi = r >> 7;                     // 0:i 1:f 2:g 3:o
            EGp[((((size_t)m * 2 + d) * 128 + u) << 2) + gi] = acc[i][jn] + bias[nn];
        }
    }
}

// ---------------------------------------------------------------------------
// Kernel 2: MFMA-batched LSTM recurrence + ragged segment max-pool.
//
// Round-16 fix: grid was 16 blocks ("8 sample-groups" — arithmetic bug:
// 64 samples / 16 per block = 4 groups). Blocks 8-15 read lens/sentence
// out of bounds -> GPU memory fault (round-16 core dump). grid = 8 blocks
// (4 sample-groups x 2 dirs). Everything else unchanged from round 9.
//
//   Batch 16 SAME-DIRECTION samples per block as the N dim of
//   mfma_f32_16x16x32_f16. preact[512 x 16] = Whh[512 x 128] @ H[128 x 16]
//   = 32 MFMA per wave per step for 16 chains at once.
//   Gate rows reordered as R = 4u + {0:i,1:f,2:g,3:o}: with the verified
//   C/D layout (col = lane&15 = sample, row = (lane>>4)*4 + reg), each lane
//   holds all 4 gate preacts of (unit, sample) in its 4 acc regs ->
//   c/h update is lane-local, no cross-lane ops at all.
// Per chain: 4 waves; wave wv owns units [32wv, 32wv+32).
// Lane: n = l&15 (sample), q = l>>4. Per M-tile m: unit u = 32wv+4m+q.
// H published to LDS (row stride 136 f16); one lgkm-only barrier per step;
// EG float4 gather with distance-2 in-place prefetch (proven pattern).
// ---------------------------------------------------------------------------

#define UU(M_) (wv * 32 + (M_) * 4 + q)

#define STEP(T_, E_, TK_, ISSUE_)                                            \
  {                                                                          \
    const int buf_ = (T_) & 1;                                               \
    const _Float16* hb_ = &Hlds[buf_][n][q * 8];                             \
    f16x8 B0_ = *(const f16x8*)(hb_ +  0);                                   \
    f16x8 B1_ = *(const f16x8*)(hb_ + 32);                                   \
    f16x8 B2_ = *(const f16x8*)(hb_ + 64);                                   \
    f16x8 B3_ = *(const f16x8*)(hb_ + 96);                                   \
    float h_[8];                                                             \
    _Pragma("unroll")                                                        \
    for (int m = 0; m < 8; ++m) {                                            \
      f32x4 a_ = {0.f, 0.f, 0.f, 0.f};                                       \
      a_ = __builtin_amdgcn_mfma_f32_16x16x32_f16(Af[m][0], B0_, a_, 0,0,0); \
      a_ = __builtin_amdgcn_mfma_f32_16x16x32_f16(Af[m][1], B1_, a_, 0,0,0); \
      a_ = __builtin_amdgcn_mfma_f32_16x16x32_f16(Af[m][2], B2_, a_, 0,0,0); \
      a_ = __builtin_amdgcn_mfma_f32_16x16x32_f16(Af[m][3], B3_, a_, 0,0,0); \
      float4 e_ = (E_)[m];          /* capture BEFORE in-place reload */     \
      if (ISSUE_)                                                            \
        (E_)[m] = eg4[((size_t)(TK_) * 2 + dir) * 128 + UU(m)]; /* T_+2 */   \
      float pi_ = a_[0] + e_.x, pf_ = a_[1] + e_.y;                          \
      float pg_ = a_[2] + e_.z, po_ = a_[3] + e_.w;                          \
      float si_ = sigf(pi_), sf_ = sigf(pf_);                                \
      float tg_ = tanh_fast(pg_), so_ = sigf(po_);                           \
      cst[m] = sf_ * cst[m] + si_ * tg_;                                     \
      h_[m] = so_ * tanh_fast(cst[m]);                                       \
    }                                                                        \
    if ((T_) < L) {   /* per-lane (per-sample) pooling, masked past L */     \
      const int tt_ = dir ? (L - 1 - (T_)) : (T_);                           \
      bool bnd_ = dir ? (tt_ < nb) : (tt_ >= nb);                            \
      if (bnd_) {                                                            \
        float base_ = (haspad && cur_seg >= padlo) ? 0.f : -INFINITY;        \
        _Pragma("unroll")                                                    \
        for (int m = 0; m < 8; ++m) {                                        \
          pws[(((size_t)b * 2 + dir) * SS + cur_seg) * H2 + UU(m)] =         \
              fmaxf(pm[m], base_);                                           \
          pm[m] = -INFINITY;                                                 \
        }                                                                    \
        cur_seg += dir ? -1 : 1;                                             \
        nb += dir ? -wseg : wseg;                                            \
      }                                                                      \
      _Pragma("unroll")                                                      \
      for (int m = 0; m < 8; ++m) pm[m] = fmaxf(pm[m], h_[m]);               \
      if ((T_) == L - 1) {                                                   \
        float base_ = (haspad && cur_seg >= padlo) ? 0.f : -INFINITY;        \
        _Pragma("unroll")                                                    \
        for (int m = 0; m < 8; ++m)                                          \
          pws[(((size_t)b * 2 + dir) * SS + cur_seg) * H2 + UU(m)] =         \
              fmaxf(pm[m], base_);                                           \
      }                                                                      \
    }                                                                        \
    _Pragma("unroll")                                                        \
    for (int m = 0; m < 8; ++m)                                              \
      Hlds[buf_ ^ 1][n][UU(m)] = (_Float16)h_[m];                            \
    lds_barrier();                                                           \
    if (ISSUE_) (TK_) = srow[tix((T_) + 4)];   /* token for T_+4 */          \
  }

__global__ __launch_bounds__(256, 1) void lstm_rec(
    const int* __restrict__ sentence, const int* __restrict__ lens,
    const float* __restrict__ Whhf, const float* __restrict__ Whhb,
    const float* __restrict__ EG4, float* __restrict__ pws)
{
    const int bid = blockIdx.x;          // 8 blocks: 4 sample-groups x 2 dirs
    const int dir = bid & 1;
    const int b0  = (bid >> 1) * 16;     // sample group base: 0,16,32,48
    const int tid = threadIdx.x;
    const int l   = tid & 63;
    const int wv  = tid >> 6;            // wave 0..3
    const int n   = l & 15;              // sample slot (B/D column)
    const int q   = l >> 4;              // k-chunk / D-subrow group
    const int b   = b0 + n;              // global sample (0..63)
    const int L   = lens[b];
    const int Lmax = lens[b0];           // lens sorted descending
    const int* __restrict__ srow = sentence + (size_t)b * TT;
    const float* __restrict__ Wh = dir ? Whhb : Whhf;
    const float4* __restrict__ eg4 = (const float4*)EG4;

    // token index for step t of this lane's sample (clamped)
    auto tix = [&](int t) -> int {
        int i = dir ? (L - 1 - t) : t;
        return max(0, min(TT - 1, i));
    };

    // --- A fragments: Whh rows reordered R=4u+gi, f16. 128 VGPRs. ---
    // A[i][k] for tile (m,kt): lane holds row i=l&15, k = kt*32 + q*8 + j.
    f16x8 Af[8][4];
    #pragma unroll
    for (int m = 0; m < 8; ++m) {
        const int R = wv * 128 + m * 16 + (l & 15);
        const int r = (R & 3) * 128 + (R >> 2);       // original gate row
        const float* src = Wh + (size_t)r * H2 + q * 8;
        #pragma unroll
        for (int kt = 0; kt < 4; ++kt) {
            float4 lo = *(const float4*)(src + kt * 32);
            float4 hi = *(const float4*)(src + kt * 32 + 4);
            f16x8 a;
            a[0] = (_Float16)lo.x; a[1] = (_Float16)lo.y;
            a[2] = (_Float16)lo.z; a[3] = (_Float16)lo.w;
            a[4] = (_Float16)hi.x; a[5] = (_Float16)hi.y;
            a[6] = (_Float16)hi.z; a[7] = (_Float16)hi.w;
            Af[m][kt] = a;
        }
    }

    // H double buffer: [buf][sample][unit], row stride 136 f16.
    __shared__ __align__(16) _Float16 Hlds[2][16][136];
    {
        int* hz = (int*)&Hlds[0][0][0];
        for (int i = tid; i < (16 * 136) / 2; i += 256) hz[i] = 0;
    }

    float cst[8], pm[8];
    #pragma unroll
    for (int m = 0; m < 8; ++m) { cst[m] = 0.f; pm[m] = -INFINITY; }

    // per-lane (per-sample) ragged pooling bookkeeping
    const int wseg = (L + SS - 1) >> 3;
    const bool haspad = (SS * wseg > L);
    const int padlo = L / wseg;
    int cur_seg = dir ? (SS - 1) : 0;
    int nb = dir ? (SS - 1) * wseg : wseg;

    // --- EG prefetch: float4 gates for t=0,1 in flight; tokens t=2,3 ---
    float4 eA[8], eB[8];
    int tokA, tokB;
    {
        int tk = srow[tix(0)];
        #pragma unroll
        for (int m = 0; m < 8; ++m)
            eA[m] = eg4[((size_t)tk * 2 + dir) * 128 + UU(m)];
        tk = srow[tix(1)];
        #pragma unroll
        for (int m = 0; m < 8; ++m)
            eB[m] = eg4[((size_t)tk * 2 + dir) * 128 + UU(m)];
        tokA = srow[tix(2)];
        tokB = srow[tix(3)];
    }

    __syncthreads();                     // Hlds[0] init visible

    int t = 0;
    for (; t + 2 <= Lmax; t += 2) {
        STEP(t,     eA, tokA, true);
        STEP(t + 1, eB, tokB, true);
    }
    if (t < Lmax) {                      // odd-Lmax tail
        STEP(t, eA, tokA, false);
    }
}

// ---------------------------------------------------------------------------
// Kernel 3: out[b,c] = b_dense[c] + sum_k flat[b,k] * W_dense[c,k]
// ---------------------------------------------------------------------------
__global__ __launch_bounds__(256) void dense_k(
    const float* __restrict__ pws, const float* __restrict__ Wd,
    const float* __restrict__ bd, float* __restrict__ out)
{
    const int b = blockIdx.x;
    const int tid = threadIdx.x;
    float a0 = 0.f, a1 = 0.f;
    for (int k = tid; k < 2048; k += 256) {
        int h = k >> 3, s = k & 7;
        int dir = h >> 7, j = h & 127;
        float v = pws[(((size_t)b * 2 + dir) * SS + s) * H2 + j];
        a0 = fmaf(v, Wd[k], a0);
        a1 = fmaf(v, Wd[2048 + k], a1);
    }
    __shared__ float r0[256], r1[256];
    r0[tid] = a0; r1[tid] = a1;
    __syncthreads();
    for (int s = 128; s > 0; s >>= 1) {
        if (tid < s) { r0[tid] += r0[tid + s]; r1[tid] += r1[tid + s]; }
        __syncthreads();
    }
    if (tid == 0) {
        out[b * 2 + 0] = r0[0] + bd[0];
        out[b * 2 + 1] = r1[0] + bd[1];
    }
}

// ---------------------------------------------------------------------------
extern "C" void kernel_launch(void* const* d_in, const int* in_sizes, int n_in,
                              void* d_out, int out_size, void* d_ws, size_t ws_size,
                              hipStream_t stream)
{
    const int*   sentence = (const int*)d_in[0];
    const int*   lens     = (const int*)d_in[1];
    const float* emb      = (const float*)d_in[2];
    const float* Wihf     = (const float*)d_in[3];
    const float* Whhf     = (const float*)d_in[4];
    const float* bf       = (const float*)d_in[5];
    const float* Wihb     = (const float*)d_in[6];
    const float* Whhb     = (const float*)d_in[7];
    const float* bb       = (const float*)d_in[8];
    const float* Wd       = (const float*)d_in[9];
    const float* bd       = (const float*)d_in[10];
    float* out = (float*)d_out;

    float* EG4 = (float*)d_ws;                    // [4096][2][128][4] fp32 = 16 MB
    float* pws = EG4 + (size_t)VV * 1024;         // [64][2][8][128] fp32 = 512 KB

    eg_gemm<<<dim3(16, 64), 256, 0, stream>>>(emb, Wihf, bf, Wihb, bb, EG4);
    lstm_rec<<<8, 256, 0, stream>>>(sentence, lens, Whhf, Whhb, EG4, pws);
    dense_k<<<64, 256, 0, stream>>>(pws, Wd, bd, out);
}

// Round 19
// 1268.101 us; speedup vs baseline: 3.0129x; 3.0129x over previous
//
#include <hip/hip_runtime.h>
#include <hip/hip_bf16.h>
#include <math.h>

// Problem constants (from reference)
#define BB 64
#define TT 2048
#define VV 4096
#define EE 128
#define H2 128
#define SS 8
#define CC 2

typedef _Float16 h2f __attribute__((ext_vector_type(2)));

// Fast reciprocal: without -ffast-math, 1.f/x compiles to the precise
// v_div_scale/v_div_fmas/v_div_fixup sequence (~15 instr). v_rcp_f32 is
// 1 trans op at ~1 ulp — round-18 post-mortem identified the precise
// divides inside sigmoid/tanh as a major serial-path cost.
__device__ __forceinline__ float fast_rcp(float x) {
#if __has_builtin(__builtin_amdgcn_rcpf)
    return __builtin_amdgcn_rcpf(x);
#else
    return 1.f / x;
#endif
}

__device__ __forceinline__ float sigf(float x) {
    return fast_rcp(1.f + __expf(-x));
}
__device__ __forceinline__ float tanh_fast(float x) {
    return fmaf(-2.f, fast_rcp(__expf(2.f * x) + 1.f), 1.f);
}

__device__ __forceinline__ float dot2acc(h2f w, h2f h, float acc) {
#if __has_builtin(__builtin_amdgcn_fdot2)
    return __builtin_amdgcn_fdot2(w, h, acc, false);
#else
    return fmaf((float)w.x, (float)h.x, fmaf((float)w.y, (float)h.y, acc));
#endif
}

// lane^1 swap as pure-VALU DPP (quad_perm [1,0,3,2] = ctrl 0xB1), ~4 cy,
// replacing __shfl_xor's LDS-pipe ds_swizzle (~100+ cy exposed at low occupancy).
__device__ __forceinline__ float xor1_swap(float x) {
#if __has_builtin(__builtin_amdgcn_update_dpp)
    return __builtin_bit_cast(float,
        __builtin_amdgcn_update_dpp(0, __builtin_bit_cast(int, x),
                                    0xB1, 0xF, 0xF, true));
#else
    return __shfl_xor(x, 1, 64);
#endif
}

// LDS-only barrier: __syncthreads() emits s_waitcnt vmcnt(0) lgkmcnt(0);
// we only need LDS consistency for the h publish, so wait on lgkmcnt alone
// and let the compiler's tracked vmcnt wait land at the EG consumption point.
__device__ __forceinline__ void lds_barrier() {
    asm volatile("s_waitcnt lgkmcnt(0)" ::: "memory");
    __builtin_amdgcn_s_barrier();
    asm volatile("" ::: "memory");
}

// ---------------------------------------------------------------------------
// Kernel 1: EG gate-bias table, PAIR layout for the recurrence:
//   EGp[v][d][p] = float2{ gate rA(p), gate rB(p) },  p in [0,256)
//   p<128  : rA = p       (i_u, u=p),    rB = 128+p (f_u)
//   p>=128 : rA = 128+p   (g_u, u=p-128), rB = 256+p (o_u)
// ---------------------------------------------------------------------------
__global__ __launch_bounds__(256) void eg_gemm(
    const float* __restrict__ emb,
    const float* __restrict__ Wf, const float* __restrict__ bf,
    const float* __restrict__ Wb, const float* __restrict__ bb,
    float* __restrict__ EGp)
{
    __shared__ float As[64][68];
    __shared__ float Bs[64][68];

    const int tid = threadIdx.x;
    const int tx = tid & 15, ty = tid >> 4;
    const int m0 = blockIdx.y * 64;
    const int n0 = blockIdx.x * 64;

    const float* Bsrc;
    const float* bias;
    if (n0 < 512) { Bsrc = Wf + n0 * EE; bias = bf + n0; }
    else          { Bsrc = Wb + (n0 - 512) * EE; bias = bb + (n0 - 512); }

    float acc[4][4] = {};

    for (int kc = 0; kc < 2; ++kc) {
        for (int c = tid; c < 1024; c += 256) {
            int r = c >> 4, q = c & 15;
            float4 av = *(const float4*)(emb + (size_t)(m0 + r) * EE + kc * 64 + q * 4);
            As[q * 4 + 0][r] = av.x; As[q * 4 + 1][r] = av.y;
            As[q * 4 + 2][r] = av.z; As[q * 4 + 3][r] = av.w;
            float4 bv = *(const float4*)(Bsrc + (size_t)r * EE + kc * 64 + q * 4);
            Bs[q * 4 + 0][r] = bv.x; Bs[q * 4 + 1][r] = bv.y;
            Bs[q * 4 + 2][r] = bv.z; Bs[q * 4 + 3][r] = bv.w;
        }
        __syncthreads();
        #pragma unroll 8
        for (int k = 0; k < 64; ++k) {
            float4 a4 = *(const float4*)&As[k][4 * ty];
            float4 b4 = *(const float4*)&Bs[k][4 * tx];
            float a[4] = {a4.x, a4.y, a4.z, a4.w};
            float b[4] = {b4.x, b4.y, b4.z, b4.w};
            #pragma unroll
            for (int i = 0; i < 4; ++i)
                #pragma unroll
                for (int jn = 0; jn < 4; ++jn)
                    acc[i][jn] = fmaf(a[i], b[jn], acc[i][jn]);
        }
        __syncthreads();
    }

    #pragma unroll
    for (int i = 0; i < 4; ++i) {
        int m = m0 + 4 * ty + i;                 // vocab index v
        #pragma unroll
        for (int jn = 0; jn < 4; ++jn) {
            int nn = 4 * tx + jn;
            int n = n0 + nn;                     // combined gate col
            int d = n >> 9;
            int r = n & 511;
            int slot = (r >> 7) & 1;
            int p = (r & 127) + (r >= 256 ? 128 : 0);
            EGp[(((size_t)m * 2 + d) * 256 + p) * 2 + slot] = acc[i][jn] + bias[nn];
        }
    }
}

// ---------------------------------------------------------------------------
// Kernel 2: fused LSTM recurrence + ragged segment max-pool.
// REVERT to the measured-best round-3 structure (1330 us lstm_rec):
// grid = 128 blocks (b,dir), 256 threads = 4 waves, 1 wave/SIMD.
// Wave w, lane l: unit u = w*32 + (l>>1).
//   even lane: W_hh rows (i_u, f_u); odd lane: rows (g_u, o_u).
// h broadcast via uniform-address ds_read_b128 (conflict-free); pair gate
// exchange via DPP quad_perm; EG distance-2 in-place prefetch; LDS-only
// per-step barrier.
// Round-18 lesson: wall = L_max x per-step LATENCY (all chains already
// parallel); MFMA 16-chain batching raised step latency 2.5x -> reverted.
// This round's single change vs the 1330 us base: v_rcp_f32 instead of
// precise IEEE divides inside sigf/tanh_fast (4 divides/lane/step ~15
// instr each were on the serial gate path).
// ---------------------------------------------------------------------------

#define LSTM_STEP(T_, BUF_, XV_, TOKN_, ISSUE_)                              \
  {                                                                          \
    float2 xv_ = (XV_);          /* capture BEFORE in-place reload */        \
    if (ISSUE_) {                                                            \
      (XV_) = egp[((size_t)(TOKN_) * 2 + dir) * 256 + p];   /* for T_+2 */   \
      int i4_ = dir ? (L - 5 - (T_)) : ((T_) + 4);          /* tok T_+4 */   \
      i4_ = max(0, min(TT - 1, i4_));                                        \
      (TOKN_) = srow[i4_];                                                   \
    }                                                                        \
    float a00 = 0.f, a01 = 0.f, a10 = 0.f, a11 = 0.f;                       \
    _Pragma("unroll")                                                        \
    for (int k4 = 0; k4 < 16; ++k4) {                                        \
      int4 hc = *(const int4*)&hpk[BUF_][4 * k4];   /* broadcast b128 */     \
      h2f hv0 = __builtin_bit_cast(h2f, hc.x);                               \
      h2f hv1 = __builtin_bit_cast(h2f, hc.y);                               \
      h2f hv2 = __builtin_bit_cast(h2f, hc.z);                               \
      h2f hv3 = __builtin_bit_cast(h2f, hc.w);                               \
      a00 = dot2acc(w0[4 * k4 + 0], hv0, a00);                               \
      a10 = dot2acc(w1[4 * k4 + 0], hv0, a10);                               \
      a01 = dot2acc(w0[4 * k4 + 1], hv1, a01);                               \
      a11 = dot2acc(w1[4 * k4 + 1], hv1, a11);                               \
      a00 = dot2acc(w0[4 * k4 + 2], hv2, a00);                               \
      a10 = dot2acc(w1[4 * k4 + 2], hv2, a10);                               \
      a01 = dot2acc(w0[4 * k4 + 3], hv3, a01);                               \
      a11 = dot2acc(w1[4 * k4 + 3], hv3, a11);                               \
    }                                                                        \
    float g0 = (a00 + a01) + xv_.x;  /* even: i-preact ; odd: g-preact */    \
    float g1 = (a10 + a11) + xv_.y;  /* even: f-preact ; odd: o-preact */    \
    float s_own = sigf(g1);                            /* sf | so */         \
    float t_own = evn ? sigf(g0) : tanh_fast(g0);      /* si | tg */         \
    float t_x = xor1_swap(t_own);                                            \
    float s_x = xor1_swap(s_own);                                            \
    c = s_own * c + t_own * t_x;                                             \
    float hn = s_x * tanh_fast(c);                                           \
    const int tt_ = dir ? (L - 1 - (T_)) : (T_);                             \
    bool bnd_ = dir ? (tt_ < nb) : (tt_ >= nb);                              \
    if (bnd_) {                                                              \
      if (evn) {                                                             \
        float v = pm;                                                        \
        if (haspad && cur_seg >= padlo) v = fmaxf(v, 0.f);                   \
        pws[(((size_t)b * 2 + dir) * SS + cur_seg) * H2 + u] = v;            \
      }                                                                      \
      pm = -INFINITY;                                                        \
      cur_seg += dir ? -1 : 1;                                               \
      nb += dir ? -wseg : wseg;                                              \
    }                                                                        \
    pm = fmaxf(pm, hn);                                                      \
    if (evn) ((_Float16*)hpk[(BUF_) ^ 1])[u] = (_Float16)hn;                 \
    lds_barrier();                                                           \
  }

__global__ __launch_bounds__(256, 1) void lstm_rec(
    const int* __restrict__ sentence, const int* __restrict__ lens,
    const float* __restrict__ Whhf, const float* __restrict__ Whhb,
    const float* __restrict__ EGp, float* __restrict__ pws)
{
    const int bid = blockIdx.x;
    const int b = bid >> 1;
    const int dir = bid & 1;            // 0 = forward, 1 = backward
    const int tid = threadIdx.x;
    const int l = tid & 63;             // lane in wave
    const int wv = tid >> 6;            // wave 0..3
    const int u = wv * 32 + (l >> 1);   // hidden unit this lane pair covers
    const bool evn = (l & 1) == 0;      // even lane: (i,f) + cell state
    const int L = lens[b];
    const int* __restrict__ srow = sentence + (size_t)b * TT;

    // rows of W_hh this lane owns (i/f on even, g/o on odd)
    const int r0 = evn ? u : (256 + u);
    const int r1 = r0 + 128;
    const float* __restrict__ Wh = (dir == 0 ? Whhf : Whhb);

    // --- W_hh rows -> packed f16 pairs: 128 arch VGPRs ---
    h2f w0[64], w1[64];
    #pragma unroll
    for (int k4 = 0; k4 < 32; ++k4) {
        float4 a = *(const float4*)(Wh + (size_t)r0 * H2 + 4 * k4);
        w0[2 * k4 + 0].x = (_Float16)a.x; w0[2 * k4 + 0].y = (_Float16)a.y;
        w0[2 * k4 + 1].x = (_Float16)a.z; w0[2 * k4 + 1].y = (_Float16)a.w;
        float4 bq = *(const float4*)(Wh + (size_t)r1 * H2 + 4 * k4);
        w1[2 * k4 + 0].x = (_Float16)bq.x; w1[2 * k4 + 0].y = (_Float16)bq.y;
        w1[2 * k4 + 1].x = (_Float16)bq.z; w1[2 * k4 + 1].y = (_Float16)bq.w;
    }

    __shared__ __align__(16) int hpk[2][64];   // double-buffered packed f16 h pairs
    if (tid < 64) hpk[0][tid] = 0;

    // per-lane EG pair column
    const int p = evn ? u : (128 + u);
    const float2* __restrict__ egp = (const float2*)EGp;
    // element index for token v: (v*2+dir)*256 + p

    float c = 0.f;
    float pm = -INFINITY;

    const int wseg = (L + SS - 1) >> 3;
    const bool haspad = (SS * wseg > L);
    const int padlo = L / wseg;
    int cur_seg = dir ? (SS - 1) : 0;
    int nb = dir ? (SS - 1) * wseg : wseg;

    // --- prefetch pipeline: EG pairs for t=0,1 in flight; tokens for t=2,3 staged ---
    float2 e0, e1;
    int tokA, tokB;
    {
        int j0 = dir ? (L - 1) : 0;
        e0 = egp[((size_t)srow[j0] * 2 + dir) * 256 + p];
        int j1 = dir ? (L - 2) : 1;  j1 = max(0, min(TT - 1, j1));
        e1 = egp[((size_t)srow[j1] * 2 + dir) * 256 + p];
        int j2 = dir ? (L - 3) : 2;  j2 = max(0, min(TT - 1, j2));
        tokA = srow[j2];
        int j3 = dir ? (L - 4) : 3;  j3 = max(0, min(TT - 1, j3));
        tokB = srow[j3];
    }

    __syncthreads();                    // hpk[0] init visible (full drain ok here)

    int t = 0;
    for (; t + 2 <= L; t += 2) {
        LSTM_STEP(t,     0, e0, tokA, true);
        LSTM_STEP(t + 1, 1, e1, tokB, true);
    }
    if (t < L) {                        // odd-L tail (t even -> buf 0)
        LSTM_STEP(t, 0, e0, tokA, false);
    }

    if (evn) {
        float v = pm;
        if (haspad && cur_seg >= padlo) v = fmaxf(v, 0.f);
        pws[(((size_t)b * 2 + dir) * SS + cur_seg) * H2 + u] = v;
    }
}

// ---------------------------------------------------------------------------
// Kernel 3: out[b,c] = b_dense[c] + sum_k flat[b,k] * W_dense[c,k]
// ---------------------------------------------------------------------------
__global__ __launch_bounds__(256) void dense_k(
    const float* __restrict__ pws, const float* __restrict__ Wd,
    const float* __restrict__ bd, float* __restrict__ out)
{
    const int b = blockIdx.x;
    const int tid = threadIdx.x;
    float a0 = 0.f, a1 = 0.f;
    for (int k = tid; k < 2048; k += 256) {
        int h = k >> 3, s = k & 7;
        int dir = h >> 7, j = h & 127;
        float v = pws[(((size_t)b * 2 + dir) * SS + s) * H2 + j];
        a0 = fmaf(v, Wd[k], a0);
        a1 = fmaf(v, Wd[2048 + k], a1);
    }
    __shared__ float r0[256], r1[256];
    r0[tid] = a0; r1[tid] = a1;
    __syncthreads();
    for (int s = 128; s > 0; s >>= 1) {
        if (tid < s) { r0[tid] += r0[tid + s]; r1[tid] += r1[tid + s]; }
        __syncthreads();
    }
    if (tid == 0) {
        out[b * 2 + 0] = r0[0] + bd[0];
        out[b * 2 + 1] = r1[0] + bd[1];
    }
}

// ---------------------------------------------------------------------------
extern "C" void kernel_launch(void* const* d_in, const int* in_sizes, int n_in,
                              void* d_out, int out_size, void* d_ws, size_t ws_size,
                              hipStream_t stream)
{
    const int*   sentence = (const int*)d_in[0];
    const int*   lens     = (const int*)d_in[1];
    const float* emb      = (const float*)d_in[2];
    const float* Wihf     = (const float*)d_in[3];
    const float* Whhf     = (const float*)d_in[4];
    const float* bf       = (const float*)d_in[5];
    const float* Wihb     = (const float*)d_in[6];
    const float* Whhb     = (const float*)d_in[7];
    const float* bb       = (const float*)d_in[8];
    const float* Wd       = (const float*)d_in[9];
    const float* bd       = (const float*)d_in[10];
    float* out = (float*)d_out;

    float* EGp = (float*)d_ws;                    // [4096][2][256][2] fp32 = 16 MB
    float* pws = EGp + (size_t)VV * 1024;         // [64][2][8][128] fp32 = 512 KB

    eg_gemm<<<dim3(16, 64), 256, 0, stream>>>(emb, Wihf, bf, Wihb, bb, EGp);
    lstm_rec<<<128, 256, 0, stream>>>(sentence, lens, Whhf, Whhb, EGp, pws);
    dense_k<<<64, 256, 0, stream>>>(pws, Wd, bd, out);
}